// Round 3
// baseline (340.339 us; speedup 1.0000x reference)
//
#include <hip/hip_runtime.h>
#include <cmath>

#define LRALPHA 0.2f

namespace {
constexpr int BB = 4;
constexpr int NN = 4096;
constexpr int ROWS = BB * NN;   // 16384
}

typedef __attribute__((ext_vector_type(8))) _Float16 f16x8;
typedef __attribute__((ext_vector_type(2))) _Float16 f16x2;
typedef __attribute__((ext_vector_type(4))) float f32x4;

union F16x8u { f16x8 v; f16x2 h[4]; };

// ---------- fused h + prep kernel ----------
// 64 rows/block, 256 threads. Lane caches W[:,lane] in 64 VGPRs. h staged in
// LDS -> fp16 (RNE, rel err <= 2^-11) stored in MFMA-B-coalesced layout:
//   hI[b][j>>3][ch][j&7]  (flat: (b<<18) + ((j>>3)<<9) + (ch<<3) + (j&7))
// Per row also computes s1 = h.a1, s2 = h.a2 and the exp-precomputes (no
// max-shift; unit-variance scores keep everything in range; the shift cancels
// in the ratio):
//   A = e^{s1}, A' = e^{0.2 s1}  (f32, row side)
//   B = e^{s2}, B' = e^{0.2 s2}  (fp16, col side -> k_attn consumes them
//                                 directly with v_pk_mul/v_pk_max, no cvt)
// Hot-loop weight: w_ij = max(A_i*B_j, A'_i*B'_j)   [= lrelu-softmax weight,
// since e^t >= e^{0.2t} iff t >= 0]. fp16 range check: s1,s2 ~ N(0,1) over
// 16K samples -> max(s1+s2) ~ 8.5 -> w <= ~5e3 << 65504; B <= e^4.4 ~ 81.
// w-quantization cancels in the softmax ratio (bf16-w round measured the
// identical absmax), so 3x2^-11 rel err is safe.
__global__ __launch_bounds__(256) void k_hcvt(
    const float* __restrict__ feat, const float* __restrict__ W,
    const float* __restrict__ a,
    unsigned short* __restrict__ hT,
    float* __restrict__ Ag, float* __restrict__ Apg,
    unsigned short* __restrict__ Bh, unsigned short* __restrict__ Bph) {
  __shared__ float tile[64][65];
  const int lane = threadIdx.x & 63;
  const int wave = threadIdx.x >> 6;
  const int row0 = blockIdx.x * 64;    // 256 blocks; never straddles a batch

  float wreg[64];
#pragma unroll
  for (int k = 0; k < 64; ++k) wreg[k] = W[k * 64 + lane];  // coalesced, once
  const float a1 = a[lane], a2 = a[64 + lane];

  for (int r = 0; r < 16; ++r) {
    const int row = row0 + wave * 16 + r;
    const float4* f4 = (const float4*)(feat + (size_t)row * 64);  // wave-uniform
    float hv = 0.f;
#pragma unroll
    for (int kk = 0; kk < 16; ++kk) {
      float4 f = f4[kk];
      hv = fmaf(f.x, wreg[4 * kk + 0], hv);
      hv = fmaf(f.y, wreg[4 * kk + 1], hv);
      hv = fmaf(f.z, wreg[4 * kk + 2], hv);
      hv = fmaf(f.w, wreg[4 * kk + 3], hv);
    }
    tile[wave * 16 + r][lane] = hv;
    float p1 = hv * a1, p2 = hv * a2;
#pragma unroll
    for (int off = 32; off; off >>= 1) {
      p1 += __shfl_xor(p1, off, 64);
      p2 += __shfl_xor(p2, off, 64);
    }
    if (lane == 0) {
      Ag[row]  = expf(p1);
      Apg[row] = expf(LRALPHA * p1);
      _Float16 b16  = (_Float16)expf(p2);
      _Float16 bp16 = (_Float16)expf(LRALPHA * p2);
      Bh[row]  = *reinterpret_cast<unsigned short*>(&b16);
      Bph[row] = *reinterpret_cast<unsigned short*>(&bp16);
    }
  }
  __syncthreads();

  // cvt + interleaved store: lane = n within 64-row tile, wave picks channels
  const int b = row0 >> 12;
  const int n0 = row0 & (NN - 1);      // multiple of 64
  const size_t base = ((size_t)b << 18) + ((size_t)(n0 >> 3) << 9)
                    + ((size_t)(lane >> 3) << 9) + (lane & 7);
#pragma unroll
  for (int cc = 0; cc < 16; ++cc) {
    int ch = cc * 4 + wave;
    float v = tile[lane][ch];          // stride 65: 2-way bank alias (free)
    _Float16 hv16 = (_Float16)v;       // v_cvt_f16_f32, RNE
    hT[base + (ch << 3)] = *reinterpret_cast<unsigned short*>(&hv16);
  }
}

// ---------- fused attention kernel ----------
// Block: 512 threads = 8 waves; 64 rows x 64 ch (was 32: doubling rows/block
// halves the per-block-amortized h stream -> L2 h-traffic 256 MB -> 128 MB,
// the dominant controllable term). Waves split j 8 ways; each wave reuses
// the SAME 4 h fragments for 4 row-groups (16 numerator + 4 denominator
// MFMAs/iter). Grid = 256 blocks x 8 waves = 2 waves/SIMD: grid-limited, so
// __launch_bounds__(512, 2) (VGPR cap 256) costs nothing and avoids spill
// for the 20x f32x4 accumulators.
// w built fully packed: per PAIR of j, v_pk_mul_f16 x2 + v_pk_max_f16 ->
// result lands directly in the fp16 MFMA-A fragment. Denominator via ones-B
// MFMA with IDENTICAL weights (w-quantization cancels in the ratio).
__global__ __launch_bounds__(512, 2) void k_attn(
    const unsigned short* __restrict__ hT,
    const float* __restrict__ Ag, const float* __restrict__ Apg,
    const unsigned short* __restrict__ Bh, const unsigned short* __restrict__ Bph,
    float* __restrict__ out) {
  __shared__ float slab[4][64][65];   // 66.6 KB: 1 block/CU (256 blocks, 256 CU)
  __shared__ float l_lds[4][64];

  const int wave = threadIdx.x >> 6;   // 0..7
  const int lane = threadIdx.x & 63;
  const int m = lane & 15;             // A row within subtile / D col (channel)
  const int quad = lane >> 4;
  const int row0 = blockIdx.x * 64;    // 256 blocks
  const int b = row0 >> 12;

  // row-side exp factors, broadcast into both halves of a packed fp16 pair
  f16x2 Arpk[4], Appk[4];
#pragma unroll
  for (int g = 0; g < 4; ++g) {
    float Ar = Ag[row0 + 16 * g + m], Ap = Apg[row0 + 16 * g + m];
    Arpk[g] = f16x2{(_Float16)Ar, (_Float16)Ar};
    Appk[g] = f16x2{(_Float16)Ap, (_Float16)Ap};
  }

  f32x4 acc[4][4];   // [row group][ch group]
  f32x4 lacc[4];     // [row group] denominator
#pragma unroll
  for (int g = 0; g < 4; ++g) {
    lacc[g] = f32x4{0, 0, 0, 0};
#pragma unroll
    for (int c = 0; c < 4; ++c) acc[g][c] = f32x4{0, 0, 0, 0};
  }

  f16x8 ones;
#pragma unroll
  for (int e = 0; e < 8; ++e) ones[e] = (_Float16)1.0f;

  const int j0 = wave * (NN / 8) + quad * 8;         // within batch
  const unsigned short* Bq  = Bh  + (b << 12) + j0;
  const unsigned short* Bpq = Bph + (b << 12) + j0;
  // hI layout: element (j, ch) at (b<<18) + ((j>>3)<<9) + (ch<<3) + (j&7).
  const unsigned short* hp = hT + ((size_t)b << 18)
                           + ((size_t)(j0 >> 3) << 9) + (m << 3);
  constexpr int ITERS = NN / 8 / 32;                 // 16

  // prologue: load iteration 0's B/Bp (8 consecutive fp16 = one dwordx4) + h
  f16x8 cB  = *(const f16x8*)Bq;
  f16x8 cBp = *(const f16x8*)Bpq;
  f16x8 hh0 = *(const f16x8*)(hp);          // ch group m
  f16x8 hh1 = *(const f16x8*)(hp + 128);    // ch group m+16
  f16x8 hh2 = *(const f16x8*)(hp + 256);    // ch group m+32
  f16x8 hh3 = *(const f16x8*)(hp + 384);    // ch group m+48

  for (int it = 0; it < ITERS; ++it) {
    // prefetch next iteration's B/Bp and h (pads make the last one in-bounds)
    Bq += 32; Bpq += 32;
    hp += 2048;                              // 4 j8-blocks of 512 elems / iter
    f16x8 nB  = *(const f16x8*)Bq;
    f16x8 nBp = *(const f16x8*)Bpq;
    f16x8 nh0 = *(const f16x8*)(hp);
    f16x8 nh1 = *(const f16x8*)(hp + 128);
    f16x8 nh2 = *(const f16x8*)(hp + 256);
    f16x8 nh3 = *(const f16x8*)(hp + 384);

    F16x8u Bu, Bpu;
    Bu.v = cB; Bpu.v = cBp;
    F16x8u afu[4];
#pragma unroll
    for (int p = 0; p < 4; ++p) {
      f16x2 b2 = Bu.h[p], bp2 = Bpu.h[p];
#pragma unroll
      for (int g = 0; g < 4; ++g)
        afu[g].h[p] = __builtin_elementwise_max(Arpk[g] * b2, Appk[g] * bp2);
    }

#pragma unroll
    for (int g = 0; g < 4; ++g) {
      f16x8 af = afu[g].v;
      lacc[g]   = __builtin_amdgcn_mfma_f32_16x16x32_f16(af, ones, lacc[g], 0, 0, 0);
      acc[g][0] = __builtin_amdgcn_mfma_f32_16x16x32_f16(af, hh0, acc[g][0], 0, 0, 0);
      acc[g][1] = __builtin_amdgcn_mfma_f32_16x16x32_f16(af, hh1, acc[g][1], 0, 0, 0);
      acc[g][2] = __builtin_amdgcn_mfma_f32_16x16x32_f16(af, hh2, acc[g][2], 0, 0, 0);
      acc[g][3] = __builtin_amdgcn_mfma_f32_16x16x32_f16(af, hh3, acc[g][3], 0, 0, 0);
    }

    cB = nB; cBp = nBp;
    hh0 = nh0; hh1 = nh1; hh2 = nh2; hh3 = nh3;
  }

  // two-stage cross-wave combine (waves 0-3 write, then waves 4-7 add)
  const int sidx = wave & 3;
  if (wave < 4) {
#pragma unroll
    for (int g = 0; g < 4; ++g) {
#pragma unroll
      for (int reg = 0; reg < 4; ++reg) {
        int rl = 16 * g + quad * 4 + reg;
        slab[sidx][rl][m]      = acc[g][0][reg];
        slab[sidx][rl][m + 16] = acc[g][1][reg];
        slab[sidx][rl][m + 32] = acc[g][2][reg];
        slab[sidx][rl][m + 48] = acc[g][3][reg];
      }
      if (m == 0) {
#pragma unroll
        for (int reg = 0; reg < 4; ++reg)
          l_lds[sidx][16 * g + quad * 4 + reg] = lacc[g][reg];
      }
    }
  }
  __syncthreads();
  if (wave >= 4) {
#pragma unroll
    for (int g = 0; g < 4; ++g) {
#pragma unroll
      for (int reg = 0; reg < 4; ++reg) {
        int rl = 16 * g + quad * 4 + reg;
        slab[sidx][rl][m]      += acc[g][0][reg];
        slab[sidx][rl][m + 16] += acc[g][1][reg];
        slab[sidx][rl][m + 32] += acc[g][2][reg];
        slab[sidx][rl][m + 48] += acc[g][3][reg];
      }
      if (m == 0) {
#pragma unroll
        for (int reg = 0; reg < 4; ++reg)
          l_lds[sidx][16 * g + quad * 4 + reg] += lacc[g][reg];
      }
    }
  }
  __syncthreads();

  // combine + normalize + store (each thread: 8 output elements)
#pragma unroll
  for (int k = 0; k < 8; ++k) {
    int f = threadIdx.x + 512 * k;      // 0..4095
    int rl = f >> 6, c = f & 63;
    float s = slab[0][rl][c] + slab[1][rl][c] + slab[2][rl][c] + slab[3][rl][c];
    float L = l_lds[0][rl] + l_lds[1][rl] + l_lds[2][rl] + l_lds[3][rl];
    out[((size_t)(row0 + rl)) * 64 + c] = s / L;
  }
}

// ---------- launcher ----------

extern "C" void kernel_launch(void* const* d_in, const int* in_sizes, int n_in,
                              void* d_out, int out_size, void* d_ws, size_t ws_size,
                              hipStream_t stream) {
  const float* feat = (const float*)d_in[0];
  // d_in[1] = adj : UNUSED by the reference computation
  const float* W = (const float*)d_in[2];
  const float* a = (const float*)d_in[3];
  float* out = (float*)d_out;

  char* ws = (char*)d_ws;
  size_t off = 0;
  auto carve = [&](size_t bytes) -> char* {
    char* p = ws + off;
    off = (off + bytes + 255) & ~(size_t)255;
    return p;
  };
  // +4096 elements pad: k_attn's one-iteration h prefetch overshoots by up to
  // ~2050 elements on the last batch -> keep it in-bounds.
  unsigned short* hT = (unsigned short*)carve(((size_t)ROWS * 64 + 4096) * sizeof(unsigned short)); // 2 MB
  float* Ag  = (float*)carve(ROWS * sizeof(float));
  float* Apg = (float*)carve(ROWS * sizeof(float));
  unsigned short* Bh  = (unsigned short*)carve((ROWS + 64) * sizeof(unsigned short)); // +64: prefetch pad
  unsigned short* Bph = (unsigned short*)carve((ROWS + 64) * sizeof(unsigned short)); // +64: prefetch pad

  k_hcvt<<<ROWS / 64, 256, 0, stream>>>(feat, W, a, hT, Ag, Apg, Bh, Bph);
  k_attn<<<ROWS / 64, 512, 0, stream>>>(hT, Ag, Apg, Bh, Bph, out);
}

// Round 4
// 329.265 us; speedup vs baseline: 1.0336x; 1.0336x over previous
//
#include <hip/hip_runtime.h>
#include <cmath>

#define LRALPHA 0.2f

namespace {
constexpr int BB = 4;
constexpr int NN = 4096;
constexpr int ROWS = BB * NN;   // 16384
}

typedef __attribute__((ext_vector_type(8))) _Float16 f16x8;
typedef __attribute__((ext_vector_type(2))) _Float16 f16x2;
typedef __attribute__((ext_vector_type(4))) float f32x4;

union F16x8u { f16x8 v; f16x2 h[4]; };

// ---------- fused h + prep kernel ----------
// 64 rows/block, 256 threads, 1 wave/SIMD (grid-limited) -> all latency must
// be hidden by ILP, so:
//  - dot product split into 4 independent fmaf chains (crit path 256->64 cyc)
//  - all 16 rows' butterfly reductions batched (16 independent shfl chains)
//  - exps distributed across lanes (cndmask select tree; lanes 0-15 do the
//    s1-exps, lanes 16-31 the s2-exps) instead of 64 serial expf on lane 0.
// h staged in LDS -> fp16 (RNE, rel err <= 2^-11) stored in MFMA-B-coalesced
// layout: hI[b][j>>3][ch][j&7] (flat: (b<<18)+((j>>3)<<9)+(ch<<3)+(j&7)).
// Exp-precomputes (no max-shift; unit-variance scores stay in range; the
// shift cancels in the softmax ratio):
//   A = e^{s1}, A' = e^{0.2 s1}  (f32, row side)
//   B = e^{s2}, B' = e^{0.2 s2}  (fp16, col side -> k_attn consumes packed)
// Hot-loop weight: w_ij = max(A_i*B_j, A'_i*B'_j)  [= lrelu-softmax weight,
// since e^t >= e^{0.2t} iff t >= 0]. fp16 range: max(s1+s2) ~ 8.5 over 16K
// N(0,1) samples -> w <= ~5e3 << 65504. w-quantization cancels in the ratio.
__global__ __launch_bounds__(256) void k_hcvt(
    const float* __restrict__ feat, const float* __restrict__ W,
    const float* __restrict__ a,
    unsigned short* __restrict__ hT,
    float* __restrict__ Ag, float* __restrict__ Apg,
    unsigned short* __restrict__ Bh, unsigned short* __restrict__ Bph) {
  __shared__ float tile[64][65];
  const int lane = threadIdx.x & 63;
  const int wave = threadIdx.x >> 6;
  const int row0 = blockIdx.x * 64;    // 256 blocks; never straddles a batch

  float wreg[64];
#pragma unroll
  for (int k = 0; k < 64; ++k) wreg[k] = W[k * 64 + lane];  // coalesced, once
  const float a1 = a[lane], a2 = a[64 + lane];

  float p1r[16], p2r[16];
#pragma unroll
  for (int r = 0; r < 16; ++r) {       // FULL unroll: p1r/p2r must stay in regs
    const int row = row0 + wave * 16 + r;
    const float4* f4 = (const float4*)(feat + (size_t)row * 64);  // wave-uniform
    float hx = 0.f, hy = 0.f, hz = 0.f, hw = 0.f;   // 4 indep chains
#pragma unroll
    for (int kk = 0; kk < 16; ++kk) {
      float4 f = f4[kk];
      hx = fmaf(f.x, wreg[4 * kk + 0], hx);
      hy = fmaf(f.y, wreg[4 * kk + 1], hy);
      hz = fmaf(f.z, wreg[4 * kk + 2], hz);
      hw = fmaf(f.w, wreg[4 * kk + 3], hw);
    }
    float hv = (hx + hy) + (hz + hw);
    tile[wave * 16 + r][lane] = hv;
    p1r[r] = hv * a1;
    p2r[r] = hv * a2;
  }

  // 16 rows x 2 values reduced together: 32 independent shfl chains -> one
  // 6-level latency instead of 16 serial reductions.
#pragma unroll
  for (int off = 32; off; off >>= 1) {
#pragma unroll
    for (int r = 0; r < 16; ++r) {
      p1r[r] += __shfl_xor(p1r[r], off, 64);
      p2r[r] += __shfl_xor(p2r[r], off, 64);
    }
  }

  // every lane now holds all 16 reduced sums; select q[lane&15] with a
  // static cndmask tree (no runtime register indexing -> no scratch)
  const int idx = lane & 15;
  float q[16];
#pragma unroll
  for (int r = 0; r < 16; ++r) q[r] = (lane < 16) ? p1r[r] : p2r[r];
  float t8[8];
#pragma unroll
  for (int r = 0; r < 8; ++r) t8[r] = (idx & 1) ? q[2 * r + 1] : q[2 * r];
  float t4[4];
#pragma unroll
  for (int r = 0; r < 4; ++r) t4[r] = (idx & 2) ? t8[2 * r + 1] : t8[2 * r];
  float t2[2];
#pragma unroll
  for (int r = 0; r < 2; ++r) t2[r] = (idx & 4) ? t4[2 * r + 1] : t4[2 * r];
  const float sel = (idx & 8) ? t2[1] : t2[0];

  if (lane < 32) {
    const int row = row0 + wave * 16 + idx;
    float e  = expf(sel);
    float ep = expf(LRALPHA * sel);
    if (lane < 16) {             // s1 side: f32 row factors
      Ag[row]  = e;
      Apg[row] = ep;
    } else {                     // s2 side: fp16 col factors
      _Float16 b16  = (_Float16)e;
      _Float16 bp16 = (_Float16)ep;
      Bh[row]  = *reinterpret_cast<unsigned short*>(&b16);
      Bph[row] = *reinterpret_cast<unsigned short*>(&bp16);
    }
  }
  __syncthreads();

  // cvt + interleaved store: lane = n within 64-row tile, wave picks channels
  const int b = row0 >> 12;
  const int n0 = row0 & (NN - 1);      // multiple of 64
  const size_t base = ((size_t)b << 18) + ((size_t)(n0 >> 3) << 9)
                    + ((size_t)(lane >> 3) << 9) + (lane & 7);
#pragma unroll
  for (int cc = 0; cc < 16; ++cc) {
    int ch = cc * 4 + wave;
    float v = tile[lane][ch];          // stride 65: 2-way bank alias (free)
    _Float16 hv16 = (_Float16)v;       // v_cvt_f16_f32, RNE
    hT[base + (ch << 3)] = *reinterpret_cast<unsigned short*>(&hv16);
  }
}

// ---------- fused attention kernel ----------
// REVERTED to the round-2 structure (proven best): 32 rows x 64 ch per block,
// 512 blocks x 8 waves = 4 waves/SIMD. Round-3 lesson: 64-row blocks halve
// L2 h-traffic but drop occupancy to 2 waves/SIMD and the loop is latency-
// bound, not L2-BW-bound -> net regression. Keep TLP.
// w built fully packed: per PAIR of j, v_pk_mul_f16 x2 + v_pk_max_f16 ->
// result lands directly in the fp16 MFMA-A fragment. Denominator via ones-B
// MFMA with IDENTICAL weights (w-quantization cancels in the ratio).
// h single fp16; 10 MFMAs/iter; h prefetched 1 iter ahead.
__global__ __launch_bounds__(512, 4) void k_attn(
    const unsigned short* __restrict__ hT,
    const float* __restrict__ Ag, const float* __restrict__ Apg,
    const unsigned short* __restrict__ Bh, const unsigned short* __restrict__ Bph,
    float* __restrict__ out) {
  __shared__ float slab[4][32][65];
  __shared__ float l_lds[4][32];

  const int wave = threadIdx.x >> 6;   // 0..7
  const int lane = threadIdx.x & 63;
  const int m = lane & 15;             // A row within subtile / D col (channel)
  const int quad = lane >> 4;
  const int row0 = blockIdx.x * 32;    // 512 blocks
  const int b = row0 >> 12;
  const int i0 = row0 + m, i1 = row0 + 16 + m;

  // row-side exp factors, broadcast into both halves of a packed fp16 pair
  const float Ar0 = Ag[i0], Ap0 = Apg[i0];
  const float Ar1 = Ag[i1], Ap1 = Apg[i1];
  const f16x2 Ar0pk = {(_Float16)Ar0, (_Float16)Ar0};
  const f16x2 Ap0pk = {(_Float16)Ap0, (_Float16)Ap0};
  const f16x2 Ar1pk = {(_Float16)Ar1, (_Float16)Ar1};
  const f16x2 Ap1pk = {(_Float16)Ap1, (_Float16)Ap1};

  f32x4 acc00 = {0,0,0,0}, acc01 = {0,0,0,0}, acc02 = {0,0,0,0}, acc03 = {0,0,0,0};
  f32x4 acc10 = {0,0,0,0}, acc11 = {0,0,0,0}, acc12 = {0,0,0,0}, acc13 = {0,0,0,0};
  f32x4 lacc0 = {0,0,0,0}, lacc1 = {0,0,0,0};

  f16x8 ones;
#pragma unroll
  for (int e = 0; e < 8; ++e) ones[e] = (_Float16)1.0f;

  const int j0 = wave * (NN / 8) + quad * 8;         // within batch
  const unsigned short* Bq  = Bh  + (b << 12) + j0;
  const unsigned short* Bpq = Bph + (b << 12) + j0;
  // hI layout: element (j, ch) at (b<<18) + ((j>>3)<<9) + (ch<<3) + (j&7).
  const unsigned short* hp = hT + ((size_t)b << 18)
                           + ((size_t)(j0 >> 3) << 9) + (m << 3);
  constexpr int ITERS = NN / 8 / 32;                 // 16

  // prologue: load iteration 0's B/Bp (8 consecutive fp16 = one dwordx4) + h
  f16x8 cB  = *(const f16x8*)Bq;
  f16x8 cBp = *(const f16x8*)Bpq;
  f16x8 hh0 = *(const f16x8*)(hp);          // ch group m
  f16x8 hh1 = *(const f16x8*)(hp + 128);    // ch group m+16
  f16x8 hh2 = *(const f16x8*)(hp + 256);    // ch group m+32
  f16x8 hh3 = *(const f16x8*)(hp + 384);    // ch group m+48

  for (int it = 0; it < ITERS; ++it) {
    // prefetch next iteration's B/Bp and h (pads make the last one in-bounds)
    Bq += 32; Bpq += 32;
    hp += 2048;                              // 4 j8-blocks of 512 elems / iter
    f16x8 nB  = *(const f16x8*)Bq;
    f16x8 nBp = *(const f16x8*)Bpq;
    f16x8 nh0 = *(const f16x8*)(hp);
    f16x8 nh1 = *(const f16x8*)(hp + 128);
    f16x8 nh2 = *(const f16x8*)(hp + 256);
    f16x8 nh3 = *(const f16x8*)(hp + 384);

    F16x8u Bu, Bpu, af0u, af1u;
    Bu.v = cB; Bpu.v = cBp;
#pragma unroll
    for (int p = 0; p < 4; ++p) {
      f16x2 b2 = Bu.h[p], bp2 = Bpu.h[p];
      af0u.h[p] = __builtin_elementwise_max(Ar0pk * b2, Ap0pk * bp2);
      af1u.h[p] = __builtin_elementwise_max(Ar1pk * b2, Ap1pk * bp2);
    }
    f16x8 af0 = af0u.v, af1 = af1u.v;

    lacc0 = __builtin_amdgcn_mfma_f32_16x16x32_f16(af0, ones, lacc0, 0, 0, 0);
    lacc1 = __builtin_amdgcn_mfma_f32_16x16x32_f16(af1, ones, lacc1, 0, 0, 0);
    acc00 = __builtin_amdgcn_mfma_f32_16x16x32_f16(af0, hh0, acc00, 0, 0, 0);
    acc01 = __builtin_amdgcn_mfma_f32_16x16x32_f16(af0, hh1, acc01, 0, 0, 0);
    acc02 = __builtin_amdgcn_mfma_f32_16x16x32_f16(af0, hh2, acc02, 0, 0, 0);
    acc03 = __builtin_amdgcn_mfma_f32_16x16x32_f16(af0, hh3, acc03, 0, 0, 0);
    acc10 = __builtin_amdgcn_mfma_f32_16x16x32_f16(af1, hh0, acc10, 0, 0, 0);
    acc11 = __builtin_amdgcn_mfma_f32_16x16x32_f16(af1, hh1, acc11, 0, 0, 0);
    acc12 = __builtin_amdgcn_mfma_f32_16x16x32_f16(af1, hh2, acc12, 0, 0, 0);
    acc13 = __builtin_amdgcn_mfma_f32_16x16x32_f16(af1, hh3, acc13, 0, 0, 0);

    cB = nB; cBp = nBp;
    hh0 = nh0; hh1 = nh1; hh2 = nh2; hh3 = nh3;
  }

  // two-stage cross-wave combine (waves 0-3 write, then waves 4-7 add)
  const int sidx = wave & 3;
  if (wave < 4) {
#pragma unroll
    for (int reg = 0; reg < 4; ++reg) {
      int rl = quad * 4 + reg;
      slab[sidx][rl][m]      = acc00[reg];
      slab[sidx][rl][m + 16] = acc01[reg];
      slab[sidx][rl][m + 32] = acc02[reg];
      slab[sidx][rl][m + 48] = acc03[reg];
      slab[sidx][16 + rl][m]      = acc10[reg];
      slab[sidx][16 + rl][m + 16] = acc11[reg];
      slab[sidx][16 + rl][m + 32] = acc12[reg];
      slab[sidx][16 + rl][m + 48] = acc13[reg];
    }
    if (m == 0) {
#pragma unroll
      for (int reg = 0; reg < 4; ++reg) {
        l_lds[sidx][quad * 4 + reg]      = lacc0[reg];
        l_lds[sidx][16 + quad * 4 + reg] = lacc1[reg];
      }
    }
  }
  __syncthreads();
  if (wave >= 4) {
#pragma unroll
    for (int reg = 0; reg < 4; ++reg) {
      int rl = quad * 4 + reg;
      slab[sidx][rl][m]      += acc00[reg];
      slab[sidx][rl][m + 16] += acc01[reg];
      slab[sidx][rl][m + 32] += acc02[reg];
      slab[sidx][rl][m + 48] += acc03[reg];
      slab[sidx][16 + rl][m]      += acc10[reg];
      slab[sidx][16 + rl][m + 16] += acc11[reg];
      slab[sidx][16 + rl][m + 32] += acc12[reg];
      slab[sidx][16 + rl][m + 48] += acc13[reg];
    }
    if (m == 0) {
#pragma unroll
      for (int reg = 0; reg < 4; ++reg) {
        l_lds[sidx][quad * 4 + reg]      += lacc0[reg];
        l_lds[sidx][16 + quad * 4 + reg] += lacc1[reg];
      }
    }
  }
  __syncthreads();

  // combine + normalize + store (each thread: 4 output elements)
#pragma unroll
  for (int k = 0; k < 4; ++k) {
    int f = threadIdx.x + 512 * k;      // 0..2047
    int rl = f >> 6, c = f & 63;
    float s = slab[0][rl][c] + slab[1][rl][c] + slab[2][rl][c] + slab[3][rl][c];
    float L = l_lds[0][rl] + l_lds[1][rl] + l_lds[2][rl] + l_lds[3][rl];
    out[((size_t)(row0 + rl)) * 64 + c] = s / L;
  }
}

// ---------- launcher ----------

extern "C" void kernel_launch(void* const* d_in, const int* in_sizes, int n_in,
                              void* d_out, int out_size, void* d_ws, size_t ws_size,
                              hipStream_t stream) {
  const float* feat = (const float*)d_in[0];
  // d_in[1] = adj : UNUSED by the reference computation
  const float* W = (const float*)d_in[2];
  const float* a = (const float*)d_in[3];
  float* out = (float*)d_out;

  char* ws = (char*)d_ws;
  size_t off = 0;
  auto carve = [&](size_t bytes) -> char* {
    char* p = ws + off;
    off = (off + bytes + 255) & ~(size_t)255;
    return p;
  };
  // +4096 elements pad: k_attn's one-iteration h prefetch overshoots by up to
  // ~2050 elements on the last batch -> keep it in-bounds.
  unsigned short* hT = (unsigned short*)carve(((size_t)ROWS * 64 + 4096) * sizeof(unsigned short)); // 2 MB
  float* Ag  = (float*)carve(ROWS * sizeof(float));
  float* Apg = (float*)carve(ROWS * sizeof(float));
  unsigned short* Bh  = (unsigned short*)carve((ROWS + 64) * sizeof(unsigned short)); // +64: prefetch pad
  unsigned short* Bph = (unsigned short*)carve((ROWS + 64) * sizeof(unsigned short)); // +64: prefetch pad

  k_hcvt<<<ROWS / 64, 256, 0, stream>>>(feat, W, a, hT, Ag, Apg, Bh, Bph);
  k_attn<<<ROWS / 32, 512, 0, stream>>>(hT, Ag, Apg, Bh, Bph, out);
}